// Round 1
// baseline (492.409 us; speedup 1.0000x reference)
//
#include <hip/hip_runtime.h>
#include <math.h>

// CurricularFace penalty softmax loss, forward only.
// B=1024 rows, C=85742 cols, fp32 logits in (-0.99, 0.99), int32 labels.
// Output: single fp32 scalar loss.

#define BB 1024
#define CC 85742
#define SS 64.0f
#define KCOS_M 0.8775825618903728f     // cos(0.5)
#define KSIN_M 0.4794255386042030f     // sin(0.5)
#define KTHRESH (-0.8775825618903728f) // cos(pi - 0.5)
#define KMM 0.2397127693021015f        // sin(pi - 0.5) * 0.5

// ---------------------------------------------------------------------------
// Kernel 1: gather target logits, reduce their sum into ws[0].
// 4 blocks x 256 threads = 1024 threads, one per row.
// ---------------------------------------------------------------------------
__global__ __launch_bounds__(256) void cf_gather_kernel(
    const float* __restrict__ logits,
    const int* __restrict__ labels,
    float* __restrict__ sum_t) {
  const int row = blockIdx.x * 256 + threadIdx.x;
  float ty = logits[(size_t)row * CC + labels[row]];
  // wave64 butterfly-free down-reduce
  #pragma unroll
  for (int off = 32; off > 0; off >>= 1)
    ty += __shfl_down(ty, off, 64);
  __shared__ float wsum[4];
  const int lane = threadIdx.x & 63;
  const int wv = threadIdx.x >> 6;
  if (lane == 0) wsum[wv] = ty;
  __syncthreads();
  if (threadIdx.x == 0)
    atomicAdd(sum_t, wsum[0] + wsum[1] + wsum[2] + wsum[3]);
}

// ---------------------------------------------------------------------------
// Kernel 2: one block per row. Stream the row once (float2 loads, 8B-aligned
// for every row since CC is even), online sum of exp(S*new_logit - 64),
// then fix up the target column and emit -L/B via atomicAdd.
// ---------------------------------------------------------------------------
__global__ __launch_bounds__(256) void cf_row_kernel(
    const float* __restrict__ logits,
    const int* __restrict__ labels,
    const float* __restrict__ sum_t,
    float* __restrict__ out) {
  const int row = blockIdx.x;

  __shared__ float sh_ty, sh_t;
  if (threadIdx.x == 0) {
    sh_ty = logits[(size_t)row * CC + labels[row]];
    sh_t = 0.01f * (*sum_t) * (1.0f / BB);  // t = 0.01 * mean(target_logit)
  }
  __syncthreads();
  const float ty = sh_ty;
  const float t = sh_t;
  // cos(theta + m) = ty*cos(m) - sqrt(1-ty^2)*sin(m)
  const float ctm = ty * KCOS_M - sqrtf(fmaxf(1.0f - ty * ty, 0.0f)) * KSIN_M;

  const float2* __restrict__ rowp =
      reinterpret_cast<const float2*>(logits + (size_t)row * CC);
  const int NV = CC / 2;  // 42871, exact (CC even)

  float acc = 0.0f;
  for (int i = threadIdx.x; i < NV; i += 256) {
    const float2 v = rowp[i];
    const float x0 = v.x, x1 = v.y;
    // hard-example reweight: x > ctm ? x*(t+x) : x
    const float n0 = (x0 > ctm) ? x0 * (t + x0) : x0;
    const float n1 = (x1 > ctm) ? x1 * (t + x1) : x1;
    acc += __expf(fmaf(SS, n0, -64.0f));
    acc += __expf(fmaf(SS, n1, -64.0f));
  }

  // block reduction
  #pragma unroll
  for (int off = 32; off > 0; off >>= 1)
    acc += __shfl_down(acc, off, 64);
  __shared__ float wsum[4];
  const int lane = threadIdx.x & 63;
  const int wv = threadIdx.x >> 6;
  if (lane == 0) wsum[wv] = acc;
  __syncthreads();

  if (threadIdx.x == 0) {
    float sum = wsum[0] + wsum[1] + wsum[2] + wsum[3];
    // The loop processed the target column as a regular element; its
    // contribution used EXACTLY this expression, so subtraction cancels it
    // bit-exactly, then add the margin-adjusted target term.
    const float modY = (ty > ctm) ? ty * (t + ty) : ty;
    const float finalT = (ty > KTHRESH) ? ctm : (ty - KMM);
    sum += __expf(fmaf(SS, finalT, -64.0f)) - __expf(fmaf(SS, modY, -64.0f));
    const float lse = logf(sum) + 64.0f;   // fixed-offset logsumexp
    const float L = SS * finalT - lse;
    atomicAdd(out, -L * (1.0f / BB));
  }
}

extern "C" void kernel_launch(void* const* d_in, const int* in_sizes, int n_in,
                              void* d_out, int out_size, void* d_ws, size_t ws_size,
                              hipStream_t stream) {
  const float* logits = (const float*)d_in[0];
  const int* labels = (const int*)d_in[1];
  float* out = (float*)d_out;
  float* sum_t = (float*)d_ws;

  // ws/out are poisoned 0xAA before every timed call — zero what we use.
  hipMemsetAsync(sum_t, 0, sizeof(float), stream);
  hipMemsetAsync(out, 0, sizeof(float), stream);

  cf_gather_kernel<<<BB / 256, 256, 0, stream>>>(logits, labels, sum_t);
  cf_row_kernel<<<BB, 256, 0, stream>>>(logits, labels, sum_t, out);
}

// Round 3
// 473.419 us; speedup vs baseline: 1.0401x; 1.0401x over previous
//
#include <hip/hip_runtime.h>
#include <math.h>

// CurricularFace penalty softmax loss, forward only.
// B=1024 rows, C=85742 cols, fp32 logits in (-0.99, 0.99), int32 labels.
// Output: single fp32 scalar loss.
//
// Single-pass trick: |S*new_logit| < 64 always (inputs are cosines, reweight
// keeps |x*(t+x)| < 1), so logsumexp uses a FIXED offset of 64 instead of a
// per-row max -> one streaming pass over the 351 MB logits tensor.

#define BB 1024
#define CC 85742
#define SS 64.0f
#define KCOS_M 0.8775825618903728f     // cos(0.5)
#define KSIN_M 0.4794255386042030f     // sin(0.5)
#define KTHRESH (-0.8775825618903728f) // cos(pi - 0.5)
#define KMM 0.2397127693021015f        // sin(pi - 0.5) * 0.5
// 64 * log2(e): exp(64*n - 64) == exp2(K2E*n - K2E)
#define K2E 92.33248261689366f

// ---------------------------------------------------------------------------
// Kernel 1: gather target logits, reduce their sum into ws[0].
// ---------------------------------------------------------------------------
__global__ __launch_bounds__(256) void cf_gather_kernel(
    const float* __restrict__ logits,
    const int* __restrict__ labels,
    float* __restrict__ sum_t) {
  const int row = blockIdx.x * 256 + threadIdx.x;
  float ty = logits[(size_t)row * CC + labels[row]];
  #pragma unroll
  for (int off = 32; off > 0; off >>= 1)
    ty += __shfl_down(ty, off, 64);
  __shared__ float wsum[4];
  const int lane = threadIdx.x & 63;
  const int wv = threadIdx.x >> 6;
  if (lane == 0) wsum[wv] = ty;
  __syncthreads();
  if (threadIdx.x == 0)
    atomicAdd(sum_t, wsum[0] + wsum[1] + wsum[2] + wsum[3]);
}

// per-element transform: exp(S*reweight(x) - 64) via exp2
__device__ __forceinline__ float cf_elem(float x, float t, float ctm) {
  const float n = (x > ctm) ? x * (t + x) : x;
  return exp2f(fmaf(K2E, n, -K2E));
}

// ---------------------------------------------------------------------------
// Kernel 2: one block per row, 8x-unrolled float2 stream (8 independent
// loads in flight per thread), online sum of exp(S*new_logit - 64), then
// fix up the target column and emit -L/B via atomicAdd.
// ---------------------------------------------------------------------------
__global__ __launch_bounds__(256) void cf_row_kernel(
    const float* __restrict__ logits,
    const int* __restrict__ labels,
    const float* __restrict__ sum_t,
    float* __restrict__ out) {
  const int row = blockIdx.x;

  __shared__ float sh_ty, sh_t;
  if (threadIdx.x == 0) {
    sh_ty = logits[(size_t)row * CC + labels[row]];
    sh_t = 0.01f * (*sum_t) * (1.0f / BB);  // t = 0.01 * mean(target_logit)
  }
  __syncthreads();
  const float ty = sh_ty;
  const float t = sh_t;
  const float ctm = ty * KCOS_M - sqrtf(fmaxf(1.0f - ty * ty, 0.0f)) * KSIN_M;

  const float2* __restrict__ rowp =
      reinterpret_cast<const float2*>(logits + (size_t)row * CC);
  constexpr int NV = CC / 2;            // 42871 float2, exact (CC even)
  constexpr int STEP = 256 * 8;         // 2048 float2 per main iteration
  constexpr int MAIN = (NV / STEP) * STEP;  // 40960

  const int tid = threadIdx.x;
  float acc = 0.0f;

  // main loop: 20 iterations, 8 independent loads in flight per thread
  for (int base = 0; base < MAIN; base += STEP) {
    float2 v0 = rowp[base + tid];
    float2 v1 = rowp[base + tid + 256];
    float2 v2 = rowp[base + tid + 512];
    float2 v3 = rowp[base + tid + 768];
    float2 v4 = rowp[base + tid + 1024];
    float2 v5 = rowp[base + tid + 1280];
    float2 v6 = rowp[base + tid + 1536];
    float2 v7 = rowp[base + tid + 1792];
    acc += cf_elem(v0.x, t, ctm) + cf_elem(v0.y, t, ctm);
    acc += cf_elem(v1.x, t, ctm) + cf_elem(v1.y, t, ctm);
    acc += cf_elem(v2.x, t, ctm) + cf_elem(v2.y, t, ctm);
    acc += cf_elem(v3.x, t, ctm) + cf_elem(v3.y, t, ctm);
    acc += cf_elem(v4.x, t, ctm) + cf_elem(v4.y, t, ctm);
    acc += cf_elem(v5.x, t, ctm) + cf_elem(v5.y, t, ctm);
    acc += cf_elem(v6.x, t, ctm) + cf_elem(v6.y, t, ctm);
    acc += cf_elem(v7.x, t, ctm) + cf_elem(v7.y, t, ctm);
  }
  // tail: 1911 float2
  for (int i = MAIN + tid; i < NV; i += 256) {
    const float2 v = rowp[i];
    acc += cf_elem(v.x, t, ctm) + cf_elem(v.y, t, ctm);
  }

  // block reduction
  #pragma unroll
  for (int off = 32; off > 0; off >>= 1)
    acc += __shfl_down(acc, off, 64);
  __shared__ float wsum[4];
  const int lane = threadIdx.x & 63;
  const int wv = threadIdx.x >> 6;
  if (lane == 0) wsum[wv] = acc;
  __syncthreads();

  if (threadIdx.x == 0) {
    float sum = wsum[0] + wsum[1] + wsum[2] + wsum[3];
    // The loop processed the target column with EXACTLY cf_elem's expression,
    // so this subtraction cancels it bit-exactly; then add the
    // margin-adjusted target term.
    const float finalT = (ty > KTHRESH) ? ctm : (ty - KMM);
    sum += exp2f(fmaf(K2E, finalT, -K2E)) - cf_elem(ty, t, ctm);
    const float lse = logf(sum) + 64.0f;  // fixed-offset logsumexp
    const float L = SS * finalT - lse;
    atomicAdd(out, -L * (1.0f / BB));
  }
}

extern "C" void kernel_launch(void* const* d_in, const int* in_sizes, int n_in,
                              void* d_out, int out_size, void* d_ws, size_t ws_size,
                              hipStream_t stream) {
  const float* logits = (const float*)d_in[0];
  const int* labels = (const int*)d_in[1];
  float* out = (float*)d_out;
  float* sum_t = (float*)d_ws;

  hipMemsetAsync(sum_t, 0, sizeof(float), stream);
  hipMemsetAsync(out, 0, sizeof(float), stream);

  cf_gather_kernel<<<BB / 256, 256, 0, stream>>>(logits, labels, sum_t);
  cf_row_kernel<<<BB, 256, 0, stream>>>(logits, labels, sum_t, out);
}

// Round 5
// 469.928 us; speedup vs baseline: 1.0478x; 1.0074x over previous
//
#include <hip/hip_runtime.h>
#include <math.h>

// CurricularFace penalty softmax loss, forward only — SINGLE fused kernel.
// B=1024 rows, C=85742 cols, fp32 logits in (-0.99, 0.99), int32 labels.
//
// Tricks:
//  * Fixed-offset logsumexp: |S*new_logit| < 64 always (cosine inputs,
//    reweight keeps |x*(t+x)| < 1), so exp(S*x - 64) never overflows ->
//    single streaming pass, no per-row max. (absmax 0.0 in prior rounds.)
//  * No grid sync for t = 0.01*mean(target): every block redundantly
//    gathers all 1024 target logits (same L2-resident lines, ~2us total)
//    with a FIXED reduction order -> bit-identical t in every block.
//  * float4 main stream: rows alternate 16B/8B alignment (CC*4 % 16 == 8),
//    peel 2 floats front (odd rows) or back (even rows) -> 21435 aligned
//    float4 per row, 8 independent loads in flight per thread.

#define BB 1024
#define CC 85742
#define SS 64.0f
#define KCOS_M 0.8775825618903728f     // cos(0.5)
#define KSIN_M 0.4794255386042030f     // sin(0.5)
#define KTHRESH (-0.8775825618903728f) // cos(pi - 0.5)
#define KMM 0.2397127693021015f        // sin(pi - 0.5) * 0.5
#define K2E 92.33248261689366f         // 64 * log2(e)
#define NV4 21435                      // float4 per row after peel
#define STEP4 2048                     // 256 threads * 8 unroll
#define MAIN4 20480                    // 10 * STEP4

// per-element transform: exp(S*reweight(x) - 64) via exp2
__device__ __forceinline__ float cf_elem(float x, float t, float ctm) {
  const float n = (x > ctm) ? x * (t + x) : x;
  return exp2f(fmaf(K2E, n, -K2E));
}

__global__ __launch_bounds__(256) void cf_fused_kernel(
    const float* __restrict__ logits,
    const int* __restrict__ labels,
    float* __restrict__ out) {
  const int row = blockIdx.x;
  const int tid = threadIdx.x;
  const int lane = tid & 63;
  const int wv = tid >> 6;

  __shared__ float wred[4];
  __shared__ float sh_t, sh_ty;

  // ---- Phase 1: block-local computation of t (identical in all blocks).
  float ts = 0.0f;
  #pragma unroll
  for (int k = 0; k < 4; ++k) {
    const int r = tid * 4 + k;
    ts += logits[(size_t)r * CC + labels[r]];
  }
  #pragma unroll
  for (int off = 32; off > 0; off >>= 1)
    ts += __shfl_down(ts, off, 64);
  if (lane == 0) wred[wv] = ts;
  if (tid == 0) sh_ty = logits[(size_t)row * CC + labels[row]];
  __syncthreads();
  if (tid == 0)
    sh_t = 0.01f * (1.0f / BB) * ((wred[0] + wred[1]) + (wred[2] + wred[3]));
  __syncthreads();

  const float t = sh_t;
  const float ty = sh_ty;
  const float ctm = ty * KCOS_M - sqrtf(fmaxf(1.0f - ty * ty, 0.0f)) * KSIN_M;

  // ---- Phase 2: stream the row, float4, 8x unroll.
  const float* __restrict__ base = logits + (size_t)row * CC;
  const int mis = (row & 1) ? 2 : 0;  // front-peel floats
  const float4* __restrict__ p4 = reinterpret_cast<const float4*>(base + mis);

  float acc = 0.0f;
  for (int b = 0; b < MAIN4; b += STEP4) {
    float4 v[8];
    #pragma unroll
    for (int u = 0; u < 8; ++u) v[u] = p4[b + tid + u * 256];
    #pragma unroll
    for (int u = 0; u < 8; ++u)
      acc += (cf_elem(v[u].x, t, ctm) + cf_elem(v[u].y, t, ctm)) +
             (cf_elem(v[u].z, t, ctm) + cf_elem(v[u].w, t, ctm));
  }
  for (int i = MAIN4 + tid; i < NV4; i += 256) {  // 955 float4 tail
    const float4 v = p4[i];
    acc += (cf_elem(v.x, t, ctm) + cf_elem(v.y, t, ctm)) +
           (cf_elem(v.z, t, ctm) + cf_elem(v.w, t, ctm));
  }
  if (tid == 0) {
    // 2 peeled scalars: front of odd rows, back of even rows
    const int i0 = mis ? 0 : (CC - 2);
    acc += cf_elem(base[i0], t, ctm) + cf_elem(base[i0 + 1], t, ctm);
  }

  // ---- Block reduction + target-column fixup.
  #pragma unroll
  for (int off = 32; off > 0; off >>= 1)
    acc += __shfl_down(acc, off, 64);
  __syncthreads();  // wred reuse guard
  if (lane == 0) wred[wv] = acc;
  __syncthreads();

  if (tid == 0) {
    float sum = wred[0] + wred[1] + wred[2] + wred[3];
    // Stream processed the target column with EXACTLY cf_elem's expression:
    // subtract it, add the margin-adjusted target term.
    const float finalT = (ty > KTHRESH) ? ctm : (ty - KMM);
    sum += exp2f(fmaf(K2E, finalT, -K2E)) - cf_elem(ty, t, ctm);
    const float lse = logf(sum) + 64.0f;  // fixed-offset logsumexp
    const float L = SS * finalT - lse;
    atomicAdd(out, -L * (1.0f / BB));
  }
}

extern "C" void kernel_launch(void* const* d_in, const int* in_sizes, int n_in,
                              void* d_out, int out_size, void* d_ws, size_t ws_size,
                              hipStream_t stream) {
  const float* logits = (const float*)d_in[0];
  const int* labels = (const int*)d_in[1];
  float* out = (float*)d_out;

  // out is poisoned 0xAA before every timed call; we accumulate into it.
  hipMemsetAsync(out, 0, sizeof(float), stream);
  cf_fused_kernel<<<BB, 256, 0, stream>>>(logits, labels, out);
}